// Round 3
// baseline (161.010 us; speedup 1.0000x reference)
//
#include <hip/hip_runtime.h>

// B=4, HG=WG=32 -> 1024 tokens/batch, 4096 total; D=768, NH=12, HD=64, K=7 (49 neighbors)

typedef __bf16 bf16x8 __attribute__((ext_vector_type(8)));
typedef short s16x4 __attribute__((ext_vector_type(4)));
typedef float f32x4 __attribute__((ext_vector_type(4)));

__device__ __forceinline__ unsigned short f2bf(float f) {
  unsigned u = __float_as_uint(f);
  u += 0x7fffu + ((u >> 16) & 1u);   // RNE
  return (unsigned short)(u >> 16);
}

template <typename T>
__device__ __forceinline__ void gld_lds16(const T* g, T* l) {
  __builtin_amdgcn_global_load_lds((const __attribute__((address_space(1))) void*)g,
                                   (__attribute__((address_space(3))) void*)l, 16, 0, 0);
}

// ---------------- fp32 -> bf16 conversion of x, qkv_w, proj_w ----------------
__global__ void cvt_kernel(const float* __restrict__ x, const float* __restrict__ w1,
                           const float* __restrict__ w2, unsigned short* __restrict__ xo,
                           unsigned short* __restrict__ w1o, unsigned short* __restrict__ w2o) {
  const int n1 = 4096 * 768 / 4;
  const int n2 = 2304 * 768 / 4;
  const int n3 = 768 * 768 / 4;
  int i = blockIdx.x * 256 + threadIdx.x;
  float4 v;
  unsigned short* dst;
  int o;
  if (i < n1) {
    o = i; v = ((const float4*)x)[o]; dst = xo;
  } else if (i < n1 + n2) {
    o = i - n1; v = ((const float4*)w1)[o]; dst = w1o;
  } else if (i < n1 + n2 + n3) {
    o = i - n1 - n2; v = ((const float4*)w2)[o]; dst = w2o;
  } else {
    return;
  }
  ushort4 r;
  r.x = f2bf(v.x); r.y = f2bf(v.y); r.z = f2bf(v.z); r.w = f2bf(v.w);
  ((ushort4*)dst)[o] = r;
}

// ---------------- bf16 GEMM, C = A * B^T + bias ----------------
// Double-buffered single-barrier K-loop; slab-K-major LDS layout (conflict-free
// ds_read_b128: each 16-lane group reads contiguous 256B).
// MT = m-tiles per wave (4 -> BM=128, 2 -> BM=64). BN=128, BK=32 fixed.
// MODE 0 (qkv): Q cols scaled by 0.125*log2(e), token-major [h][4096][64];
//               K token-major; V TRANSPOSED vt[h][64][4096].
// MODE 1 (proj): fp32 out, row-major.
template <int MT, int MODE>
__global__ __launch_bounds__(256) void gemm_bt(const unsigned short* __restrict__ A,
                                               const unsigned short* __restrict__ Bm,
                                               const float* __restrict__ bias,
                                               unsigned short* __restrict__ obf,
                                               unsigned short* __restrict__ vtout,
                                               float* __restrict__ of32,
                                               int M, int N, int Kd) {
  constexpr int BM = MT * 32;
  __shared__ __align__(16) unsigned short sA[2 * BM * 32];
  __shared__ __align__(16) unsigned short sB[2 * 128 * 32];
  const int tid = threadIdx.x;
  const int lane = tid & 63;
  const int wv = tid >> 6;
  const int m0 = blockIdx.y * BM, n0 = blockIdx.x * 128;
  const int wrow = (wv >> 1) * (MT * 16), wcol = (wv & 1) * 64;
  const int lr = lane & 15, lq = lane >> 4;

  f32x4 acc[MT][4] = {};

  // staging source: lane = (chunk lc)*16 + (row-in-slab ls); wave wv owns slab wv (+4)
  const int ls = lane & 15, lc = lane >> 4;
  const unsigned short* pA  = A  + (size_t)(m0 + wv * 16 + ls) * Kd + lc * 8;
  const unsigned short* pA2 = A  + (size_t)(m0 + (wv + 4) * 16 + ls) * Kd + lc * 8;  // MT==4 only
  const unsigned short* pB  = Bm + (size_t)(n0 + wv * 16 + ls) * Kd + lc * 8;
  const unsigned short* pB2 = Bm + (size_t)(n0 + (wv + 4) * 16 + ls) * Kd + lc * 8;

  auto stage = [&](int it, int bsel) {
    const int k0 = it * 32;
    gld_lds16(pA + k0, sA + bsel * (BM * 32) + tid * 8);
    if (MT == 4) gld_lds16(pA2 + k0, sA + bsel * (BM * 32) + 2048 + tid * 8);
    gld_lds16(pB + k0, sB + bsel * 4096 + tid * 8);
    gld_lds16(pB2 + k0, sB + bsel * 4096 + 2048 + tid * 8);
  };

  const int nIter = Kd >> 5;
  stage(0, 0);
  __syncthreads();
  for (int it = 0; it < nIter; ++it) {
    const int cur = it & 1;
    if (it + 1 < nIter) stage(it + 1, cur ^ 1);  // in flight during compute below
    const unsigned short* bA = sA + cur * (BM * 32);
    const unsigned short* bB = sB + cur * 4096;
    bf16x8 af[MT], bfr[4];
#pragma unroll
    for (int t = 0; t < MT; ++t)
      af[t] = *(const bf16x8*)(bA + ((wrow >> 4) + t) * 512 + lq * 128 + lr * 8);
#pragma unroll
    for (int t = 0; t < 4; ++t)
      bfr[t] = *(const bf16x8*)(bB + ((wcol >> 4) + t) * 512 + lq * 128 + lr * 8);
#pragma unroll
    for (int im = 0; im < MT; ++im)
#pragma unroll
      for (int in = 0; in < 4; ++in)
        acc[im][in] = __builtin_amdgcn_mfma_f32_16x16x32_bf16(af[im], bfr[in], acc[im][in], 0, 0, 0);
    __syncthreads();  // drains next tile's loads (covered by compute) + fences buf reads
  }

  if (MODE == 0) {
    const int sidx = n0 / 768;  // block-uniform (768 % 128 == 0)
    if (sidx == 2) {
      // V -> transposed vt[(hh*64+dd)*4096 + token]
#pragma unroll
      for (int im = 0; im < MT; ++im) {
#pragma unroll
        for (int in = 0; in < 4; ++in) {
          int gn = n0 + wcol + in * 16 + lr;
          int rem = gn - 1536;
          int hh = rem >> 6, dd = gn & 63;
          float bsv = bias[gn];
          int gm0 = m0 + wrow + im * 16 + lq * 4;
          ushort4 pk;
          pk.x = f2bf(acc[im][in][0] + bsv);
          pk.y = f2bf(acc[im][in][1] + bsv);
          pk.z = f2bf(acc[im][in][2] + bsv);
          pk.w = f2bf(acc[im][in][3] + bsv);
          *(ushort4*)(vtout + (size_t)(hh * 64 + dd) * 4096 + gm0) = pk;
        }
      }
    } else {
      const float scale = (sidx == 0) ? 0.18033688f : 1.0f;  // 0.125 * log2(e) for Q
#pragma unroll
      for (int im = 0; im < MT; ++im) {
#pragma unroll
        for (int in = 0; in < 4; ++in) {
          int gn = n0 + wcol + in * 16 + lr;
          int rem = gn - sidx * 768;
          int hh = rem >> 6, dd = gn & 63;
          float bsv = bias[gn];
#pragma unroll
          for (int r = 0; r < 4; ++r) {
            int gm = m0 + wrow + im * 16 + lq * 4 + r;
            float val = (acc[im][in][r] + bsv) * scale;
            obf[((size_t)(sidx * 12 + hh) * 4096 + gm) * 64 + dd] = f2bf(val);
          }
        }
      }
    }
  } else {
#pragma unroll
    for (int im = 0; im < MT; ++im) {
#pragma unroll
      for (int in = 0; in < 4; ++in) {
        int gn = n0 + wcol + in * 16 + lr;
        float bsv = bias[gn];
#pragma unroll
        for (int r = 0; r < 4; ++r) {
          int gm = m0 + wrow + im * 16 + lq * 4 + r;
          of32[(size_t)gm * N + gn] = acc[im][in][r] + bsv;
        }
      }
    }
  }
}

// ---------------- neighborhood attention (MFMA) ---------------- (unchanged)
__global__ __launch_bounds__(256, 2) void natten_kernel(const unsigned short* __restrict__ qkvt,
                                                        unsigned short* __restrict__ aout) {
  __shared__ __align__(16) unsigned short sQ[64 * 64];    //  8 KB
  __shared__ __align__(16) unsigned short sK[256 * 64];   // 32 KB
  __shared__ __align__(16) unsigned short sVt[64 * 256];  // 32 KB
  const int h = blockIdx.x, ip = blockIdx.y, b = blockIdx.z;
  const int i0 = ip * 2;
  const int tid = threadIdx.x, lane = tid & 63, wv = tid >> 6;
  const int lg = lane >> 4, lm = lane & 15;
  int si0 = i0 - 3; si0 = si0 < 0 ? 0 : si0; if (si0 > 25) si0 = 25;
  const int gb = b * 1024;
  const unsigned short* Qg = qkvt + ((size_t)h * 4096 + gb + i0 * 32) * 64;
  const unsigned short* Kg = qkvt + ((size_t)(12 + h) * 4096 + gb) * 64;
  const unsigned short* Vg = qkvt + (size_t)24 * 4096 * 64 + (size_t)h * 64 * 4096 + gb;

#pragma unroll
  for (int it = 0; it < 2; ++it) {  // Q: 64 q x 64 d
    int f = it * 256 + tid;
    int q = f >> 3, c16 = f & 7;
    uint4 v = *(const uint4*)(Qg + q * 64 + c16 * 8);
    int s = q & 15;
    *(uint2*)(sQ + q * 64 + ((((c16 << 1)) ^ s) << 2)) = make_uint2(v.x, v.y);
    *(uint2*)(sQ + q * 64 + ((((c16 << 1) | 1) ^ s) << 2)) = make_uint2(v.z, v.w);
  }
#pragma unroll
  for (int it = 0; it < 8; ++it) {  // K: 256 tok x 64 d
    int f = it * 256 + tid;
    int t = f >> 3, c16 = f & 7;
    int wr = t >> 5, c = t & 31;
    int row = si0 + wr; if (row > 31) row = 31;
    uint4 v = *(const uint4*)(Kg + (row * 32 + c) * 64 + c16 * 8);
    int s = t & 15;
    *(uint2*)(sK + t * 64 + ((((c16 << 1)) ^ s) << 2)) = make_uint2(v.x, v.y);
    *(uint2*)(sK + t * 64 + ((((c16 << 1) | 1) ^ s) << 2)) = make_uint2(v.z, v.w);
  }
#pragma unroll
  for (int it = 0; it < 8; ++it) {  // Vt: 64 d x 256 tok
    int f = it * 256 + tid;
    int d = f >> 5, tc16 = f & 31;
    int wr = tc16 >> 2;
    int row = si0 + wr; if (row > 31) row = 31;
    uint4 v = *(const uint4*)(Vg + (size_t)d * 4096 + row * 32 + (tc16 & 3) * 8);
    int s = d & 15;
    *(uint2*)(sVt + d * 256 + ((((tc16 << 1)) ^ s) << 2)) = make_uint2(v.x, v.y);
    *(uint2*)(sVt + d * 256 + ((((tc16 << 1) | 1) ^ s) << 2)) = make_uint2(v.z, v.w);
  }
  __syncthreads();

  const int row_sel = wv >> 1;
  const int jhalf = wv & 1;
  const int i = i0 + row_sel;
  int si_w = i - 3; si_w = si_w < 0 ? 0 : si_w; if (si_w > 25) si_w = 25;
  const int toff = (si_w - si0) * 32;
  const int j = jhalf * 16 + lm;
  int sj = j - 3; sj = sj < 0 ? 0 : sj; if (sj > 25) sj = 25;

  float madd[2][4];
#pragma unroll
  for (int p = 0; p < 2; ++p)
#pragma unroll
    for (int r = 0; r < 4; ++r) {
      int c = p * 16 + lg * 4 + r;
      madd[p][r] = (c >= sj && c <= sj + 6) ? 0.f : -1e30f;
    }

  s16x4 qf[4];
  const int qrow = row_sel * 32 + j;
#pragma unroll
  for (int ks = 0; ks < 4; ++ks)
    qf[ks] = *(const s16x4*)(sQ + qrow * 64 + ((((ks << 2) + lg) ^ (qrow & 15)) << 2));

  f32x4 accS[14];
#pragma unroll
  for (int tt = 0; tt < 14; ++tt) {
    f32x4 a = {0.f, 0.f, 0.f, 0.f};
    const int trow = toff + tt * 16 + lm;
    const unsigned short* kr = sK + trow * 64;
    const int sw = trow & 15;
#pragma unroll
    for (int ks = 0; ks < 4; ++ks) {
      s16x4 kf = *(const s16x4*)(kr + ((((ks << 2) + lg) ^ sw) << 2));
      a = __builtin_amdgcn_mfma_f32_16x16x16bf16_1k(kf, qf[ks], a, 0, 0, 0);
    }
    accS[tt] = a;
  }

  float mx = -3e38f;
#pragma unroll
  for (int tt = 0; tt < 14; ++tt)
#pragma unroll
    for (int r = 0; r < 4; ++r) {
      float v = accS[tt][r] + madd[tt & 1][r];
      accS[tt][r] = v;
      mx = fmaxf(mx, v);
    }
  mx = fmaxf(mx, __shfl_xor(mx, 16, 64));
  mx = fmaxf(mx, __shfl_xor(mx, 32, 64));
  float sum = 0.f;
#pragma unroll
  for (int tt = 0; tt < 14; ++tt)
#pragma unroll
    for (int r = 0; r < 4; ++r) {
      float p = exp2f(accS[tt][r] - mx);
      accS[tt][r] = p;
      sum += p;
    }
  sum += __shfl_xor(sum, 16, 64);
  sum += __shfl_xor(sum, 32, 64);
  const float inv = 1.f / sum;

  s16x4 pf[14];
#pragma unroll
  for (int tt = 0; tt < 14; ++tt) {
    union { unsigned u[2]; s16x4 v; } pk;
    pk.u[0] = ((unsigned)f2bf(accS[tt][1]) << 16) | f2bf(accS[tt][0]);
    pk.u[1] = ((unsigned)f2bf(accS[tt][3]) << 16) | f2bf(accS[tt][2]);
    pf[tt] = pk.v;
  }

  f32x4 accO[4] = {};
  const int choff = toff >> 2;
#pragma unroll
  for (int tt = 0; tt < 14; ++tt) {
    const int c8 = choff + tt * 4 + lg;
#pragma unroll
    for (int nt = 0; nt < 4; ++nt) {
      const int d = nt * 16 + lm;
      s16x4 vf = *(const s16x4*)(sVt + d * 256 + ((c8 ^ (d & 15)) << 2));
      accO[nt] = __builtin_amdgcn_mfma_f32_16x16x16bf16_1k(pf[tt], vf, accO[nt], 0, 0, 0);
    }
  }

  float invr[4];
#pragma unroll
  for (int r = 0; r < 4; ++r) invr[r] = __shfl(inv, lg * 4 + r, 64);

  const int tokbase = gb + i * 32 + jhalf * 16;
#pragma unroll
  for (int nt = 0; nt < 4; ++nt)
#pragma unroll
    for (int r = 0; r < 4; ++r) {
      int tok = tokbase + lg * 4 + r;
      aout[(size_t)tok * 768 + h * 64 + nt * 16 + lm] = f2bf(accO[nt][r] * invr[r]);
    }
}

// ---------------- launch ----------------
extern "C" void kernel_launch(void* const* d_in, const int* in_sizes, int n_in,
                              void* d_out, int out_size, void* d_ws, size_t ws_size,
                              hipStream_t stream) {
  const float* x      = (const float*)d_in[0];
  const float* qkv_w  = (const float*)d_in[1];
  const float* qkv_b  = (const float*)d_in[2];
  const float* proj_w = (const float*)d_in[3];
  const float* proj_b = (const float*)d_in[4];
  char* ws = (char*)d_ws;

  unsigned short* xb    = (unsigned short*)(ws);                 // 4096*768 bf16
  unsigned short* wqkv  = (unsigned short*)(ws + 6291456);       // 2304*768 bf16
  unsigned short* wproj = (unsigned short*)(ws + 9830400);       // 768*768 bf16
  unsigned short* qkvt  = (unsigned short*)(ws + 11010048);      // Q,K token-major + Vt
  unsigned short* attnb = (unsigned short*)(ws + 29884416);      // 4096*768 bf16
  unsigned short* vt    = qkvt + (size_t)24 * 4096 * 64;         // V transposed [12][64][4096]
  float* out = (float*)d_out;

  cvt_kernel<<<5376, 256, 0, stream>>>(x, qkv_w, proj_w, xb, wqkv, wproj);
  gemm_bt<4, 0><<<dim3(18, 32), 256, 0, stream>>>(xb, wqkv, qkv_b, qkvt, vt, nullptr, 4096, 2304, 768);
  natten_kernel<<<dim3(12, 16, 4), 256, 0, stream>>>(qkvt, attnb);
  gemm_bt<2, 1><<<dim3(6, 64), 256, 0, stream>>>(attnb, wproj, proj_b, nullptr, nullptr, out, 4096, 768, 768);
}